// Round 6
// baseline (7601.410 us; speedup 1.0000x reference)
//
#include <hip/hip_runtime.h>

#define TPB 256
#define NB1 256     // stripe blocks for edge passes
#define NBUCK 2048  // buckets of 64 dst nodes (dst>>6); supports N <= 131072

using half4_t = __attribute__((ext_vector_type(4))) _Float16;
using half8_t = __attribute__((ext_vector_type(8))) _Float16;
using f32x4 = __attribute__((ext_vector_type(4))) float;

// ---------------- bucket sort of edges (atomic-free, LDS cursors) ----------------

__global__ __launch_bounds__(256) void hist1_k(const int* __restrict__ ei,
                                               int* __restrict__ hist, int E, int stripe) {
  __shared__ int h[NBUCK];
  for (int i = threadIdx.x; i < NBUCK; i += 256) h[i] = 0;
  __syncthreads();
  int b0 = blockIdx.x * stripe;
  int b1 = min(b0 + stripe, E);
  for (int e = b0 + threadIdx.x; e < b1; e += 256) atomicAdd(&h[ei[E + e] >> 6], 1);
  __syncthreads();
  for (int i = threadIdx.x; i < NBUCK; i += 256) hist[i * NB1 + blockIdx.x] = h[i];
}

__global__ void scan1_k(const int* __restrict__ src, int* __restrict__ out,
                        int* __restrict__ chunk, int n) {
  __shared__ int sh[TPB];
  int i = blockIdx.x * TPB + threadIdx.x;
  int v = (i < n) ? src[i] : 0;
  sh[threadIdx.x] = v;
  __syncthreads();
  for (int off = 1; off < TPB; off <<= 1) {
    int t = (threadIdx.x >= off) ? sh[threadIdx.x - off] : 0;
    __syncthreads();
    sh[threadIdx.x] += t;
    __syncthreads();
  }
  if (i < n) out[i] = sh[threadIdx.x] - v;
  if (threadIdx.x == TPB - 1) chunk[blockIdx.x] = sh[TPB - 1];
}

// 1024 threads, 2 elements per thread; nb <= 2048
__global__ void scan2_k(int* __restrict__ chunk, int nb) {
  __shared__ int sh[1024];
  int t = threadIdx.x;
  int i0 = 2 * t, i1 = 2 * t + 1;
  int a = (i0 < nb) ? chunk[i0] : 0;
  int b = (i1 < nb) ? chunk[i1] : 0;
  int v = a + b;
  sh[t] = v;
  __syncthreads();
  for (int off = 1; off < 1024; off <<= 1) {
    int tv = (t >= off) ? sh[t - off] : 0;
    __syncthreads();
    sh[t] += tv;
    __syncthreads();
  }
  int ex = sh[t] - v;
  if (i0 < nb) chunk[i0] = ex;
  if (i1 < nb) chunk[i1] = ex + a;
}

__global__ void scan3_k(int* __restrict__ out, const int* __restrict__ chunk, int n) {
  int i = blockIdx.x * TPB + threadIdx.x;
  if (i < n) out[i] += chunk[blockIdx.x];
}

// pack: (dst&63)<<26 | src  (src < 2^26)
__global__ __launch_bounds__(256) void scatter1_k(const int* __restrict__ ei,
                                                  const int* __restrict__ base,
                                                  unsigned* __restrict__ ebuf, int E,
                                                  int stripe) {
  __shared__ int cur[NBUCK];
  for (int i = threadIdx.x; i < NBUCK; i += 256) cur[i] = base[i * NB1 + blockIdx.x];
  __syncthreads();
  int b0 = blockIdx.x * stripe;
  int b1 = min(b0 + stripe, E);
  for (int e = b0 + threadIdx.x; e < b1; e += 256) {
    int s = ei[e];
    int d = ei[E + e];
    int p = atomicAdd(&cur[d >> 6], 1);
    ebuf[p] = (unsigned)s | ((unsigned)(d & 63) << 26);
  }
}

// per-bucket degree count -> invd
__global__ __launch_bounds__(256) void degB_k(const unsigned* __restrict__ ebuf,
                                              const int* __restrict__ base,
                                              float* __restrict__ invd, int N, int E) {
  __shared__ int cnt[64];
  __shared__ int bse[2];
  int b = blockIdx.x, t = threadIdx.x;
  if (t == 0) {
    bse[0] = base[(size_t)b * NB1];
    bse[1] = (b + 1 < NBUCK) ? base[(size_t)(b + 1) * NB1] : E;
  }
  if (t < 64) cnt[t] = 0;
  __syncthreads();
  int bs = bse[0], be = bse[1];
  for (int e = bs + t; e < be; e += 256) atomicAdd(&cnt[ebuf[e] >> 26], 1);
  __syncthreads();
  int node = b * 64 + t;
  if (t < 64 && node < N) invd[node] = 1.0f / fmaxf((float)cnt[t], 1.0f);
}

// ---------------- fp32 -> fp16 converts ----------------

__global__ void f2h_k(const float* __restrict__ in, _Float16* __restrict__ out, int n4) {
  int i = blockIdx.x * TPB + threadIdx.x;
  if (i < n4) {
    float4 v = ((const float4*)in)[i];
    half4_t o;
    o.x = (_Float16)v.x; o.y = (_Float16)v.y; o.z = (_Float16)v.z; o.w = (_Float16)v.w;
    ((half4_t*)out)[i] = o;
  }
}

__global__ void w6_k(const float* __restrict__ w0, const float* __restrict__ w1,
                     const float* __restrict__ w2, const float* __restrict__ w3,
                     const float* __restrict__ w4, const float* __restrict__ w5,
                     _Float16* __restrict__ out) {
  int t = blockIdx.x * TPB + threadIdx.x;  // t < 6*4096 (float4 units)
  if (t >= 6 * 4096) return;
  int which = t >> 12, i = t & 4095;
  const float* src = which == 0 ? w0 : which == 1 ? w1 : which == 2 ? w2
                   : which == 3 ? w3 : which == 4 ? w4 : w5;
  float4 v = ((const float4*)src)[i];
  half4_t o;
  o.x = (_Float16)v.x; o.y = (_Float16)v.y; o.z = (_Float16)v.z; o.w = (_Float16)v.w;
  ((half4_t*)out)[(size_t)which * 4096 + i] = o;
}

// ---------------- 128-dim mean aggregation: edge-parallel, LDS accumulate ----------------
// One block per 64-node bucket. LDS acc[64][129] fp32 (stride 129: bank = dl + feat).
// Half-wave (32 lanes) gathers one full fp16 row (half4/lane); 4 edges in flight/half.

__global__ __launch_bounds__(256) void aggB128_k(
    const _Float16* __restrict__ hb, const unsigned* __restrict__ ebuf,
    const int* __restrict__ base, const float* __restrict__ invd,
    _Float16* __restrict__ out, int N, int E) {
  __shared__ float acc[64 * 129];
  __shared__ int bse[2];
  int b = blockIdx.x, t = threadIdx.x;
  if (t == 0) {
    bse[0] = base[(size_t)b * NB1];
    bse[1] = (b + 1 < NBUCK) ? base[(size_t)(b + 1) * NB1] : E;
  }
  for (int i = t; i < 64 * 129; i += 256) acc[i] = 0.f;
  __syncthreads();
  int bs = bse[0], be = bse[1];
  int half = t >> 5, l = t & 31;
  for (int e0 = bs + half * 4; e0 < be; e0 += 32) {
    int cnt = min(be - e0, 4);
    unsigned u[4];
    float4 f[4];
#pragma unroll
    for (int j = 0; j < 4; ++j) u[j] = (j < cnt) ? ebuf[e0 + j] : 0u;
#pragma unroll
    for (int j = 0; j < 4; ++j) {
      if (j < cnt) {
        int src = u[j] & 0x3FFFFFF;
        half4_t v = *(const half4_t*)&hb[(size_t)src * 128 + (l << 2)];
        f[j] = make_float4((float)v.x, (float)v.y, (float)v.z, (float)v.w);
      }
    }
#pragma unroll
    for (int j = 0; j < 4; ++j) {
      if (j < cnt) {
        int dl = u[j] >> 26;
        float* a = &acc[dl * 129 + (l << 2)];
        atomicAdd(a + 0, f[j].x);
        atomicAdd(a + 1, f[j].y);
        atomicAdd(a + 2, f[j].z);
        atomicAdd(a + 3, f[j].w);
      }
    }
  }
  __syncthreads();
  int n0 = b * 64;
  for (int idx = t; idx < 64 * 32; idx += 256) {
    int node = idx >> 5, f4 = (idx & 31) << 2;
    int gn = n0 + node;
    if (gn < N) {
      float w = invd[gn];
      float* a = &acc[node * 129 + f4];
      half4_t r;
      r.x = (_Float16)(a[0] * w); r.y = (_Float16)(a[1] * w);
      r.z = (_Float16)(a[2] * w); r.w = (_Float16)(a[3] * w);
      *(half4_t*)&out[(size_t)gn * 128 + f4] = r;
    }
  }
}

// ---------------- fused dual GEMM via f16 MFMA ----------------

__global__ __launch_bounds__(256) void gemm2_k(
    const _Float16* __restrict__ Aagg, const _Float16* __restrict__ Ah,
    const _Float16* __restrict__ Wh,  // [2][128][128]: Wl then Wr
    const float* __restrict__ bias, _Float16* __restrict__ outh, int n, int do_relu) {
  int wave = threadIdx.x >> 6;
  int lane = threadIdx.x & 63;
  int quad = lane >> 4;
  int l16 = lane & 15;
  int m0 = blockIdx.x * 64 + wave * 16;
  int arow = m0 + l16;
  bool valid = arow < n;
  size_t abase = (size_t)arow * 128 + quad * 8;

  f32x4 acc[8];
#pragma unroll
  for (int c = 0; c < 8; ++c) acc[c] = (f32x4){0.f, 0.f, 0.f, 0.f};

#pragma unroll
  for (int s = 0; s < 2; ++s) {
    const _Float16* A = s ? Ah : Aagg;
    const _Float16* W = Wh + (size_t)s * 16384;
#pragma unroll
    for (int kb = 0; kb < 128; kb += 32) {
      half8_t af;
      if (valid) {
        af = *(const half8_t*)&A[abase + kb];
      } else {
#pragma unroll
        for (int jj = 0; jj < 8; ++jj) af[jj] = (_Float16)0;
      }
#pragma unroll
      for (int c = 0; c < 8; ++c) {
        half8_t bf = *(const half8_t*)&W[(size_t)(c * 16 + l16) * 128 + kb + quad * 8];
        acc[c] = __builtin_amdgcn_mfma_f32_16x16x32_f16(af, bf, acc[c], 0, 0, 0);
      }
    }
  }

#pragma unroll
  for (int c = 0; c < 8; ++c) {
    float bcol = bias[c * 16 + l16];
#pragma unroll
    for (int r = 0; r < 4; ++r) {
      int row = m0 + quad * 4 + r;
      if (row < n) {
        float v = acc[c][r] + bcol;
        if (do_relu) v = fmaxf(v, 0.f);
        outh[(size_t)row * 128 + c * 16 + l16] = (_Float16)v;
      }
    }
  }
}

// ---------------- head weight packing (fp16 Wcat, fp32 bcat) ----------------

__global__ void pack_head_k(const float* __restrict__ Wal, const float* __restrict__ War,
                            const float* __restrict__ ba, const float* __restrict__ Wsl,
                            const float* __restrict__ Wsr, const float* __restrict__ bsx,
                            const float* __restrict__ Wel, const float* __restrict__ Wer,
                            const float* __restrict__ be, _Float16* __restrict__ Wcat,
                            float* __restrict__ bcat) {
  int t = blockIdx.x * TPB + threadIdx.x;
  float v = 0.f;
  bool ok = t < 2048;
  if (t < 384) v = Wal[t];
  else if (t < 640) v = Wsl[t - 384];
  else if (t < 1024) v = Wel[t - 640];
  else if (t < 1408) v = War[t - 1024];
  else if (t < 1664) v = Wsr[t - 1408];
  else if (t < 2048) v = Wer[t - 1664];
  if (ok) Wcat[t] = (_Float16)v;
  if (t < 16) {
    float b = 0.f;
    if (t >= 8 && t < 11) b = ba[t - 8];
    else if (t >= 11 && t < 13) b = bsx[t - 11];
    else if (t >= 13) b = be[t - 13];
    bcat[t] = b;
  }
}

// ---------------- head GEMM: out_lr[n,16] = h3 @ Wcat^T + bcat (fp16 in) ----------------

__global__ __launch_bounds__(256) void head_gemm_k(const _Float16* __restrict__ h,
                                                   const _Float16* __restrict__ Wcat,
                                                   const float* __restrict__ bcat,
                                                   float* __restrict__ out_lr, int n) {
  __shared__ float hs[64 * 132];
  __shared__ float Ws[16 * 128];
  __shared__ float bsh[16];
  int tid = threadIdx.x;
  int m0 = blockIdx.x * 64;
  {
    half8_t w = *(const half8_t*)&Wcat[tid * 8];
#pragma unroll
    for (int jj = 0; jj < 8; ++jj) Ws[tid * 8 + jj] = (float)w[jj];
    if (tid < 16) bsh[tid] = bcat[tid];
  }
  {
    int row = tid >> 2, q = tid & 3;
    int grow = m0 + row;
#pragma unroll
    for (int j = 0; j < 4; ++j) {
      half8_t v;
      if (grow < n) {
        v = *(const half8_t*)&h[(size_t)grow * 128 + q * 32 + j * 8];
      } else {
#pragma unroll
        for (int jj = 0; jj < 8; ++jj) v[jj] = (_Float16)0;
      }
#pragma unroll
      for (int jj = 0; jj < 8; ++jj) hs[row * 132 + q * 32 + j * 8 + jj] = (float)v[jj];
    }
  }
  __syncthreads();
  int row = tid & 63, og = tid >> 6;
  float acc[4] = {0.f, 0.f, 0.f, 0.f};
#pragma unroll
  for (int k4 = 0; k4 < 32; ++k4) {
    float4 hv = *(float4*)&hs[row * 132 + k4 * 4];
#pragma unroll
    for (int i = 0; i < 4; ++i) {
      float4 wv = *(float4*)&Ws[(og * 4 + i) * 128 + k4 * 4];
      acc[i] += hv.x * wv.x + hv.y * wv.y + hv.z * wv.z + hv.w * wv.w;
    }
  }
  int grow = m0 + row;
  if (grow < n) {
#pragma unroll
    for (int i = 0; i < 4; ++i)
      out_lr[(size_t)grow * 16 + og * 4 + i] = acc[i] + bsh[og * 4 + i];
  }
}

// ---------------- head aggregation: edge-parallel, LDS accumulate ----------------
// Gathers only the first 8 floats (aggregated part) of each head_lr row.
// out layout: age [n,3] @0, sex [n,2] @3n, eth [n,3] @5n

__global__ __launch_bounds__(256) void aggB8_k(
    const float* __restrict__ hlr, const unsigned* __restrict__ ebuf,
    const int* __restrict__ base, const float* __restrict__ invd,
    float* __restrict__ out, int N, int E) {
  __shared__ float acc[64 * 9];
  __shared__ int bse[2];
  int b = blockIdx.x, t = threadIdx.x;
  if (t == 0) {
    bse[0] = base[(size_t)b * NB1];
    bse[1] = (b + 1 < NBUCK) ? base[(size_t)(b + 1) * NB1] : E;
  }
  for (int i = t; i < 64 * 9; i += 256) acc[i] = 0.f;
  __syncthreads();
  int bs = bse[0], be = bse[1];
  int eighth = t >> 3, q = t & 7;  // 32 eighths of 8 lanes
  for (int e0 = bs + eighth * 4; e0 < be; e0 += 128) {
    int cnt = min(be - e0, 4);
    unsigned u[4];
    float f[4];
#pragma unroll
    for (int j = 0; j < 4; ++j) u[j] = (j < cnt) ? ebuf[e0 + j] : 0u;
#pragma unroll
    for (int j = 0; j < 4; ++j) {
      if (j < cnt) {
        int src = u[j] & 0x3FFFFFF;
        f[j] = hlr[(size_t)src * 16 + q];
      }
    }
#pragma unroll
    for (int j = 0; j < 4; ++j) {
      if (j < cnt) {
        int dl = u[j] >> 26;
        atomicAdd(&acc[dl * 9 + q], f[j]);
      }
    }
  }
  __syncthreads();
  int n0 = b * 64;
  for (int idx = t; idx < 64 * 8; idx += 256) {
    int node = idx >> 3, c = idx & 7;
    int gn = n0 + node;
    if (gn < N) {
      float r = acc[node * 9 + c] * invd[gn] + hlr[(size_t)gn * 16 + 8 + c];
      if (c < 3) out[(size_t)gn * 3 + c] = r;
      else if (c < 5) out[(size_t)3 * N + (size_t)gn * 2 + (c - 3)] = r;
      else out[(size_t)5 * N + (size_t)gn * 3 + (c - 5)] = r;
    }
  }
}

// ---------------- launch ----------------

extern "C" void kernel_launch(void* const* d_in, const int* in_sizes, int n_in,
                              void* d_out, int out_size, void* d_ws, size_t ws_size,
                              hipStream_t stream) {
  const float* x = (const float*)d_in[0];
  const int* ei = (const int*)d_in[1];
  const float* W1l = (const float*)d_in[2];
  const float* W1r = (const float*)d_in[3];
  const float* b1 = (const float*)d_in[4];
  const float* W2l = (const float*)d_in[5];
  const float* W2r = (const float*)d_in[6];
  const float* b2 = (const float*)d_in[7];
  const float* W3l = (const float*)d_in[8];
  const float* W3r = (const float*)d_in[9];
  const float* b3 = (const float*)d_in[10];
  const float* Wal = (const float*)d_in[11];
  const float* War = (const float*)d_in[12];
  const float* ba = (const float*)d_in[13];
  const float* Wsl = (const float*)d_in[14];
  const float* Wsr = (const float*)d_in[15];
  const float* bsx = (const float*)d_in[16];
  const float* Wel = (const float*)d_in[17];
  const float* Wer = (const float*)d_in[18];
  const float* be = (const float*)d_in[19];

  int N = in_sizes[0] / 128;
  int E = in_sizes[1] / 2;
  int NBKT = (N + 63) >> 6;  // used 64-node buckets

  char* w = (char*)d_ws;
  auto alloc = [&](size_t b) {
    char* p = w;
    w += (b + 255) & ~(size_t)255;
    return p;
  };
  float* invd = (float*)alloc((size_t)N * 4);
  int* hist = (int*)alloc((size_t)NBUCK * NB1 * 4);
  int* chunk = (int*)alloc(2048 * 4);
  unsigned* ebuf = (unsigned*)alloc((size_t)E * 4);  // persistent (all layers)
  _Float16* xh = (_Float16*)alloc((size_t)N * 128 * 2);
  _Float16* aggh = (_Float16*)alloc((size_t)N * 128 * 2);
  _Float16* hA = (_Float16*)alloc((size_t)N * 128 * 2);
  _Float16* hB = (_Float16*)alloc((size_t)N * 128 * 2);
  _Float16* wh = (_Float16*)alloc((size_t)6 * 16384 * 2);
  _Float16* Wcat = (_Float16*)alloc(2048 * 2);
  float* bcat = (float*)alloc(16 * 4);
  float* head_lr = (float*)alloc((size_t)N * 16 * 4);

  int stripe = (((E + NB1 - 1) / NB1) + 255) & ~255;
  int nscan = NBUCK * NB1;               // 524288
  int nbScan = (nscan + TPB - 1) / TPB;  // 2048
  int nbM = (N + 63) / 64;
  int nbC = (N * 32 + TPB - 1) / TPB;

  // bucket-sort edges (no global atomics)
  hist1_k<<<NB1, 256, 0, stream>>>(ei, hist, E, stripe);
  scan1_k<<<nbScan, TPB, 0, stream>>>(hist, hist, chunk, nscan);
  scan2_k<<<1, 1024, 0, stream>>>(chunk, nbScan);
  scan3_k<<<nbScan, TPB, 0, stream>>>(hist, chunk, nscan);
  scatter1_k<<<NB1, 256, 0, stream>>>(ei, hist, ebuf, E, stripe);
  degB_k<<<NBKT, 256, 0, stream>>>(ebuf, hist, invd, N, E);

  // fp16 conversions
  f2h_k<<<nbC, TPB, 0, stream>>>(x, xh, N * 32);
  w6_k<<<96, TPB, 0, stream>>>(W1l, W1r, W2l, W2r, W3l, W3r, wh);
  pack_head_k<<<8, TPB, 0, stream>>>(Wal, War, ba, Wsl, Wsr, bsx, Wel, Wer, be, Wcat, bcat);

  // layer 1: x -> hA
  aggB128_k<<<NBKT, 256, 0, stream>>>(xh, ebuf, hist, invd, aggh, N, E);
  gemm2_k<<<nbM, TPB, 0, stream>>>(aggh, xh, wh + 0 * 16384, b1, hA, N, 1);
  // layer 2: hA -> hB
  aggB128_k<<<NBKT, 256, 0, stream>>>(hA, ebuf, hist, invd, aggh, N, E);
  gemm2_k<<<nbM, TPB, 0, stream>>>(aggh, hA, wh + 2 * 16384, b2, hB, N, 1);
  // layer 3: hB -> hA
  aggB128_k<<<NBKT, 256, 0, stream>>>(hB, ebuf, hist, invd, aggh, N, E);
  gemm2_k<<<nbM, TPB, 0, stream>>>(aggh, hB, wh + 4 * 16384, b3, hA, N, 1);
  // heads: transform to 16 dims first, then aggregate 8-dim part
  head_gemm_k<<<nbM, TPB, 0, stream>>>(hA, Wcat, bcat, head_lr, N);
  aggB8_k<<<NBKT, 256, 0, stream>>>(head_lr, ebuf, hist, invd, (float*)d_out, N, E);
}

// Round 7
// 850.554 us; speedup vs baseline: 8.9370x; 8.9370x over previous
//
#include <hip/hip_runtime.h>

#define TPB 256
#define NB1 256    // stripe blocks for edge passes
#define NBUCK 512  // coarse buckets (dst>>8); supports N <= 131072

using half4_t = __attribute__((ext_vector_type(4))) _Float16;
using half8_t = __attribute__((ext_vector_type(8))) _Float16;
using f32x4 = __attribute__((ext_vector_type(4))) float;

// ---------------- CSR build: atomic-free MSD counting sort ----------------

__global__ __launch_bounds__(256) void hist1_k(const int* __restrict__ ei,
                                               int* __restrict__ hist, int E, int stripe) {
  __shared__ int h[NBUCK];
  for (int i = threadIdx.x; i < NBUCK; i += 256) h[i] = 0;
  __syncthreads();
  int b0 = blockIdx.x * stripe;
  int b1 = min(b0 + stripe, E);
  for (int e = b0 + threadIdx.x; e < b1; e += 256) atomicAdd(&h[ei[E + e] >> 8], 1);
  __syncthreads();
  for (int i = threadIdx.x; i < NBUCK; i += 256) hist[i * NB1 + blockIdx.x] = h[i];
}

__global__ void scan1_k(const int* __restrict__ src, int* __restrict__ out,
                        int* __restrict__ chunk, int n) {
  __shared__ int sh[TPB];
  int i = blockIdx.x * TPB + threadIdx.x;
  int v = (i < n) ? src[i] : 0;
  sh[threadIdx.x] = v;
  __syncthreads();
  for (int off = 1; off < TPB; off <<= 1) {
    int t = (threadIdx.x >= off) ? sh[threadIdx.x - off] : 0;
    __syncthreads();
    sh[threadIdx.x] += t;
    __syncthreads();
  }
  if (i < n) out[i] = sh[threadIdx.x] - v;
  if (threadIdx.x == TPB - 1) chunk[blockIdx.x] = sh[TPB - 1];
}

__global__ void scan2_k(int* __restrict__ chunk, int nb) {
  __shared__ int sh[512];
  int v = (threadIdx.x < nb) ? chunk[threadIdx.x] : 0;
  sh[threadIdx.x] = v;
  __syncthreads();
  for (int off = 1; off < 512; off <<= 1) {
    int t = (threadIdx.x >= off) ? sh[threadIdx.x - off] : 0;
    __syncthreads();
    sh[threadIdx.x] += t;
    __syncthreads();
  }
  if (threadIdx.x < nb) chunk[threadIdx.x] = sh[threadIdx.x] - v;
}

__global__ void scan3_k(int* __restrict__ out, const int* __restrict__ chunk, int n) {
  int i = blockIdx.x * TPB + threadIdx.x;
  if (i < n) out[i] += chunk[blockIdx.x];
}

// pack: src (24 bits) | low8(dst) << 24
__global__ __launch_bounds__(256) void scatter1_k(const int* __restrict__ ei,
                                                  const int* __restrict__ base,
                                                  unsigned* __restrict__ ebuf, int E,
                                                  int stripe) {
  __shared__ int cur[NBUCK];
  for (int i = threadIdx.x; i < NBUCK; i += 256) cur[i] = base[i * NB1 + blockIdx.x];
  __syncthreads();
  int b0 = blockIdx.x * stripe;
  int b1 = min(b0 + stripe, E);
  for (int e = b0 + threadIdx.x; e < b1; e += 256) {
    int s = ei[e];
    int d = ei[E + e];
    int p = atomicAdd(&cur[d >> 8], 1);
    ebuf[p] = (unsigned)s | ((unsigned)(d & 255) << 24);
  }
}

__global__ __launch_bounds__(256) void build_k(const unsigned* __restrict__ ebuf,
                                               const int* __restrict__ base,
                                               int* __restrict__ row_start,
                                               int* __restrict__ deg,
                                               float* __restrict__ invd,
                                               int* __restrict__ csr, int N, int E) {
  __shared__ int h[256];
  __shared__ int excl[256];
  __shared__ int bse[2];
  int b = blockIdx.x;
  int t = threadIdx.x;
  if (t == 0) {
    bse[0] = base[b * NB1];
    bse[1] = (b + 1 < NBUCK) ? base[(b + 1) * NB1] : E;
  }
  h[t] = 0;
  __syncthreads();
  int bs = bse[0], be = bse[1];
  for (int e = bs + t; e < be; e += 256) atomicAdd(&h[ebuf[e] >> 24], 1);
  __syncthreads();
  int v = h[t];
  excl[t] = v;
  __syncthreads();
  for (int off = 1; off < 256; off <<= 1) {
    int tv = (t >= off) ? excl[t - off] : 0;
    __syncthreads();
    excl[t] += tv;
    __syncthreads();
  }
  int ex = excl[t] - v;
  int node = b * 256 + t;
  if (node < N) {
    row_start[node] = bs + ex;
    deg[node] = v;
    invd[node] = 1.0f / fmaxf((float)v, 1.0f);
  }
  h[t] = bs + ex;
  __syncthreads();
  for (int e = bs + t; e < be; e += 256) {
    unsigned p = ebuf[e];
    int pos = atomicAdd(&h[p >> 24], 1);
    csr[pos] = (int)(p & 0xFFFFFFu);
  }
}

// ---------------- fp32 -> fp16 converts ----------------

__global__ void f2h_k(const float* __restrict__ in, _Float16* __restrict__ out, int n4) {
  int i = blockIdx.x * TPB + threadIdx.x;
  if (i < n4) {
    float4 v = ((const float4*)in)[i];
    half4_t o;
    o.x = (_Float16)v.x; o.y = (_Float16)v.y; o.z = (_Float16)v.z; o.w = (_Float16)v.w;
    ((half4_t*)out)[i] = o;
  }
}

__global__ void w6_k(const float* __restrict__ w0, const float* __restrict__ w1,
                     const float* __restrict__ w2, const float* __restrict__ w3,
                     const float* __restrict__ w4, const float* __restrict__ w5,
                     _Float16* __restrict__ out) {
  int t = blockIdx.x * TPB + threadIdx.x;  // t < 6*4096 (float4 units)
  if (t >= 6 * 4096) return;
  int which = t >> 12, i = t & 4095;
  const float* src = which == 0 ? w0 : which == 1 ? w1 : which == 2 ? w2
                   : which == 3 ? w3 : which == 4 ? w4 : w5;
  float4 v = ((const float4*)src)[i];
  half4_t o;
  o.x = (_Float16)v.x; o.y = (_Float16)v.y; o.z = (_Float16)v.z; o.w = (_Float16)v.w;
  ((half4_t*)out)[(size_t)which * 4096 + i] = o;
}

// ---------------- 128-dim mean aggregation, fp16 gather, fp16 out ----------------
// One wave per node; lanes 0-31 even rows, 32-63 odd rows; lane covers 4 features.
// 8 edges in flight per half-wave (8 independent 8B loads/lane) to cover gather latency.

__global__ void agg128_k(const _Float16* __restrict__ hb, const int* __restrict__ csr,
                         const int* __restrict__ row_start, const int* __restrict__ deg,
                         const float* __restrict__ invd, _Float16* __restrict__ out,
                         int n) {
  int node = (blockIdx.x << 2) + (threadIdx.x >> 6);
  if (node >= n) return;
  int lane = threadIdx.x & 63;
  int half = lane >> 5;
  int l = lane & 31;
  int s = row_start[node];
  int c = deg[node];
  float a0 = 0.f, a1 = 0.f, a2 = 0.f, a3 = 0.f;
  int j = 0;
  for (; j + 16 <= c; j += 16) {
    int idx[8];
#pragma unroll
    for (int p = 0; p < 8; ++p) idx[p] = csr[s + j + 2 * p + half];
    half4_t v[8];
#pragma unroll
    for (int p = 0; p < 8; ++p) v[p] = *(const half4_t*)&hb[(size_t)idx[p] * 128 + (l << 2)];
#pragma unroll
    for (int p = 0; p < 8; ++p) {
      a0 += (float)v[p].x; a1 += (float)v[p].y; a2 += (float)v[p].z; a3 += (float)v[p].w;
    }
  }
  for (; j + 2 <= c; j += 2) {
    int src = csr[s + j + half];
    half4_t v = *(const half4_t*)&hb[(size_t)src * 128 + (l << 2)];
    a0 += (float)v.x; a1 += (float)v.y; a2 += (float)v.z; a3 += (float)v.w;
  }
  if (j < c && half == 0) {
    int src = csr[s + j];
    half4_t v = *(const half4_t*)&hb[(size_t)src * 128 + (l << 2)];
    a0 += (float)v.x; a1 += (float)v.y; a2 += (float)v.z; a3 += (float)v.w;
  }
  a0 += __shfl_xor(a0, 32);
  a1 += __shfl_xor(a1, 32);
  a2 += __shfl_xor(a2, 32);
  a3 += __shfl_xor(a3, 32);
  if (half == 0) {
    float w = invd[node];
    half4_t r;
    r.x = (_Float16)(a0 * w); r.y = (_Float16)(a1 * w);
    r.z = (_Float16)(a2 * w); r.w = (_Float16)(a3 * w);
    *(half4_t*)&out[(size_t)node * 128 + (l << 2)] = r;
  }
}

// ---------------- fused dual GEMM via f16 MFMA ----------------
// outh = act(Aagg@Wl^T + Ah@Wr^T + b), fp32 accumulate, fp16 store.

__global__ __launch_bounds__(256) void gemm2_k(
    const _Float16* __restrict__ Aagg, const _Float16* __restrict__ Ah,
    const _Float16* __restrict__ Wh,  // [2][128][128]: Wl then Wr
    const float* __restrict__ bias, _Float16* __restrict__ outh, int n, int do_relu) {
  int wave = threadIdx.x >> 6;
  int lane = threadIdx.x & 63;
  int quad = lane >> 4;
  int l16 = lane & 15;
  int m0 = blockIdx.x * 64 + wave * 16;
  int arow = m0 + l16;
  bool valid = arow < n;
  size_t abase = (size_t)arow * 128 + quad * 8;

  f32x4 acc[8];
#pragma unroll
  for (int c = 0; c < 8; ++c) acc[c] = (f32x4){0.f, 0.f, 0.f, 0.f};

#pragma unroll
  for (int s = 0; s < 2; ++s) {
    const _Float16* A = s ? Ah : Aagg;
    const _Float16* W = Wh + (size_t)s * 16384;
#pragma unroll
    for (int kb = 0; kb < 128; kb += 32) {
      half8_t af;
      if (valid) {
        af = *(const half8_t*)&A[abase + kb];
      } else {
#pragma unroll
        for (int jj = 0; jj < 8; ++jj) af[jj] = (_Float16)0;
      }
#pragma unroll
      for (int c = 0; c < 8; ++c) {
        half8_t bf = *(const half8_t*)&W[(size_t)(c * 16 + l16) * 128 + kb + quad * 8];
        acc[c] = __builtin_amdgcn_mfma_f32_16x16x32_f16(af, bf, acc[c], 0, 0, 0);
      }
    }
  }

#pragma unroll
  for (int c = 0; c < 8; ++c) {
    float bcol = bias[c * 16 + l16];
#pragma unroll
    for (int r = 0; r < 4; ++r) {
      int row = m0 + quad * 4 + r;
      if (row < n) {
        float v = acc[c][r] + bcol;
        if (do_relu) v = fmaxf(v, 0.f);
        outh[(size_t)row * 128 + c * 16 + l16] = (_Float16)v;
      }
    }
  }
}

// ---------------- head weight packing (fp16 Wcat, fp32 bcat) ----------------

__global__ void pack_head_k(const float* __restrict__ Wal, const float* __restrict__ War,
                            const float* __restrict__ ba, const float* __restrict__ Wsl,
                            const float* __restrict__ Wsr, const float* __restrict__ bsx,
                            const float* __restrict__ Wel, const float* __restrict__ Wer,
                            const float* __restrict__ be, _Float16* __restrict__ Wcat,
                            float* __restrict__ bcat) {
  int t = blockIdx.x * TPB + threadIdx.x;
  float v = 0.f;
  bool ok = t < 2048;
  if (t < 384) v = Wal[t];
  else if (t < 640) v = Wsl[t - 384];
  else if (t < 1024) v = Wel[t - 640];
  else if (t < 1408) v = War[t - 1024];
  else if (t < 1664) v = Wsr[t - 1408];
  else if (t < 2048) v = Wer[t - 1664];
  if (ok) Wcat[t] = (_Float16)v;
  if (t < 16) {
    float b = 0.f;
    if (t >= 8 && t < 11) b = ba[t - 8];
    else if (t >= 11 && t < 13) b = bsx[t - 11];
    else if (t >= 13) b = be[t - 13];
    bcat[t] = b;
  }
}

// ---------------- head GEMM: split outputs hl_agg[n,8], hl_root[n,8] ----------------

__global__ __launch_bounds__(256) void head_gemm_k(const _Float16* __restrict__ h,
                                                   const _Float16* __restrict__ Wcat,
                                                   const float* __restrict__ bcat,
                                                   float* __restrict__ hl_agg,
                                                   float* __restrict__ hl_root, int n) {
  __shared__ float hs[64 * 132];
  __shared__ float Ws[16 * 128];
  __shared__ float bsh[16];
  int tid = threadIdx.x;
  int m0 = blockIdx.x * 64;
  {
    half8_t w = *(const half8_t*)&Wcat[tid * 8];
#pragma unroll
    for (int jj = 0; jj < 8; ++jj) Ws[tid * 8 + jj] = (float)w[jj];
    if (tid < 16) bsh[tid] = bcat[tid];
  }
  {
    int row = tid >> 2, q = tid & 3;
    int grow = m0 + row;
#pragma unroll
    for (int j = 0; j < 4; ++j) {
      half8_t v;
      if (grow < n) {
        v = *(const half8_t*)&h[(size_t)grow * 128 + q * 32 + j * 8];
      } else {
#pragma unroll
        for (int jj = 0; jj < 8; ++jj) v[jj] = (_Float16)0;
      }
#pragma unroll
      for (int jj = 0; jj < 8; ++jj) hs[row * 132 + q * 32 + j * 8 + jj] = (float)v[jj];
    }
  }
  __syncthreads();
  int row = tid & 63, og = tid >> 6;
  float acc[4] = {0.f, 0.f, 0.f, 0.f};
#pragma unroll
  for (int k4 = 0; k4 < 32; ++k4) {
    float4 hv = *(float4*)&hs[row * 132 + k4 * 4];
#pragma unroll
    for (int i = 0; i < 4; ++i) {
      float4 wv = *(float4*)&Ws[(og * 4 + i) * 128 + k4 * 4];
      acc[i] += hv.x * wv.x + hv.y * wv.y + hv.z * wv.z + hv.w * wv.w;
    }
  }
  int grow = m0 + row;
  if (grow < n) {
#pragma unroll
    for (int i = 0; i < 4; ++i) {
      float v = acc[i] + bsh[og * 4 + i];
      if (og < 2) hl_agg[(size_t)grow * 8 + og * 4 + i] = v;
      else hl_root[(size_t)grow * 8 + (og - 2) * 4 + i] = v;
    }
  }
}

// ---------------- 8-dim aggregation + output write ----------------
// Gathers packed 32B rows of hl_agg; root-add from hl_root.
// out layout: age [n,3] @0, sex [n,2] @3n, eth [n,3] @5n

__global__ void agg8_k(const float* __restrict__ hl_agg, const float* __restrict__ hl_root,
                       const int* __restrict__ csr, const int* __restrict__ row_start,
                       const int* __restrict__ deg, const float* __restrict__ invd,
                       float* __restrict__ out, int n) {
  int node = (blockIdx.x << 2) + (threadIdx.x >> 6);
  if (node >= n) return;
  int lane = threadIdx.x & 63;
  int c = lane & 7, g = lane >> 3;
  int s = row_start[node], cnt = deg[node];
  float acc = 0.f;
  for (int j = g; j < cnt; j += 8) {
    int src = csr[s + j];
    acc += hl_agg[(size_t)src * 8 + c];
  }
  acc += __shfl_xor(acc, 8);
  acc += __shfl_xor(acc, 16);
  acc += __shfl_xor(acc, 32);
  if (g == 0) {
    float r = acc * invd[node] + hl_root[(size_t)node * 8 + c];
    if (c < 3) out[(size_t)node * 3 + c] = r;
    else if (c < 5) out[(size_t)3 * n + (size_t)node * 2 + (c - 3)] = r;
    else out[(size_t)5 * n + (size_t)node * 3 + (c - 5)] = r;
  }
}

// ---------------- launch ----------------

extern "C" void kernel_launch(void* const* d_in, const int* in_sizes, int n_in,
                              void* d_out, int out_size, void* d_ws, size_t ws_size,
                              hipStream_t stream) {
  const float* x = (const float*)d_in[0];
  const int* ei = (const int*)d_in[1];
  const float* W1l = (const float*)d_in[2];
  const float* W1r = (const float*)d_in[3];
  const float* b1 = (const float*)d_in[4];
  const float* W2l = (const float*)d_in[5];
  const float* W2r = (const float*)d_in[6];
  const float* b2 = (const float*)d_in[7];
  const float* W3l = (const float*)d_in[8];
  const float* W3r = (const float*)d_in[9];
  const float* b3 = (const float*)d_in[10];
  const float* Wal = (const float*)d_in[11];
  const float* War = (const float*)d_in[12];
  const float* ba = (const float*)d_in[13];
  const float* Wsl = (const float*)d_in[14];
  const float* Wsr = (const float*)d_in[15];
  const float* bsx = (const float*)d_in[16];
  const float* Wel = (const float*)d_in[17];
  const float* Wer = (const float*)d_in[18];
  const float* be = (const float*)d_in[19];

  int N = in_sizes[0] / 128;
  int E = in_sizes[1] / 2;
  int NBKT = (N + 255) >> 8;

  char* w = (char*)d_ws;
  auto alloc = [&](size_t b) {
    char* p = w;
    w += (b + 255) & ~(size_t)255;
    return p;
  };
  int* deg = (int*)alloc((size_t)N * 4);
  int* row_start = (int*)alloc((size_t)N * 4);
  float* invd = (float*)alloc((size_t)N * 4);
  int* hist = (int*)alloc((size_t)NBUCK * NB1 * 4);
  int* chunk = (int*)alloc(512 * 4);
  int* csr = (int*)alloc((size_t)E * 4);
  // xh (fp16 x, N*128*2 B) aliases ebuf (E*4 B): ebuf dead after build_k.
  size_t xh_bytes = (size_t)N * 128 * 2;
  size_t ebuf_bytes = (size_t)E * 4;
  char* region = (char*)alloc(xh_bytes > ebuf_bytes ? xh_bytes : ebuf_bytes);
  unsigned* ebuf = (unsigned*)region;
  _Float16* xh = (_Float16*)region;
  _Float16* aggh = (_Float16*)alloc((size_t)N * 128 * 2);
  _Float16* hA = (_Float16*)alloc((size_t)N * 128 * 2);
  _Float16* hB = (_Float16*)alloc((size_t)N * 128 * 2);
  _Float16* wh = (_Float16*)alloc((size_t)6 * 16384 * 2);
  _Float16* Wcat = (_Float16*)alloc(2048 * 2);
  float* bcat = (float*)alloc(16 * 4);
  float* hl_agg = (float*)alloc((size_t)N * 8 * 4);
  float* hl_root = (float*)alloc((size_t)N * 8 * 4);

  int stripe = (((E + NB1 - 1) / NB1) + 255) & ~255;
  int nscan = NBUCK * NB1;
  int nbScan = (nscan + TPB - 1) / TPB;
  int nbNode = (N + 3) / 4;
  int nbM = (N + 63) / 64;
  int nbC = (N * 32 + TPB - 1) / TPB;

  // CSR build — no global atomics
  hist1_k<<<NB1, 256, 0, stream>>>(ei, hist, E, stripe);
  scan1_k<<<nbScan, TPB, 0, stream>>>(hist, hist, chunk, nscan);
  scan2_k<<<1, 512, 0, stream>>>(chunk, nbScan);
  scan3_k<<<nbScan, TPB, 0, stream>>>(hist, chunk, nscan);
  scatter1_k<<<NB1, 256, 0, stream>>>(ei, hist, ebuf, E, stripe);
  build_k<<<NBKT, 256, 0, stream>>>(ebuf, hist, row_start, deg, invd, csr, N, E);

  // fp16 conversions (xh aliases ebuf: must come after build_k)
  f2h_k<<<nbC, TPB, 0, stream>>>(x, xh, N * 32);
  w6_k<<<96, TPB, 0, stream>>>(W1l, W1r, W2l, W2r, W3l, W3r, wh);
  pack_head_k<<<8, TPB, 0, stream>>>(Wal, War, ba, Wsl, Wsr, bsx, Wel, Wer, be, Wcat, bcat);

  // layer 1: x -> hA
  agg128_k<<<nbNode, TPB, 0, stream>>>(xh, csr, row_start, deg, invd, aggh, N);
  gemm2_k<<<nbM, TPB, 0, stream>>>(aggh, xh, wh + 0 * 16384, b1, hA, N, 1);
  // layer 2: hA -> hB
  agg128_k<<<nbNode, TPB, 0, stream>>>(hA, csr, row_start, deg, invd, aggh, N);
  gemm2_k<<<nbM, TPB, 0, stream>>>(aggh, hA, wh + 2 * 16384, b2, hB, N, 1);
  // layer 3: hB -> hA
  agg128_k<<<nbNode, TPB, 0, stream>>>(hB, csr, row_start, deg, invd, aggh, N);
  gemm2_k<<<nbM, TPB, 0, stream>>>(aggh, hB, wh + 4 * 16384, b3, hA, N, 1);
  // heads: transform to 16 dims first, then aggregate packed 8-dim part
  head_gemm_k<<<nbM, TPB, 0, stream>>>(hA, Wcat, bcat, hl_agg, hl_root, N);
  agg8_k<<<nbNode, TPB, 0, stream>>>(hl_agg, hl_root, csr, row_start, deg, invd,
                                     (float*)d_out, N);
}